// Round 6
// baseline (466.519 us; speedup 1.0000x reference)
//
#include <hip/hip_runtime.h>

// Causal attention head: B=4, T=2048, C=1024, fp32 in/out.
//   k = x@Wk^T, q = x@Wq^T, v = x@Wv^T ; S = q@k^T (no scale, causal) ;
//   P = softmax(S) ; out = P@v
//
// R6 (counter-driven; R5: per-block engine OK at 39% MfmaUtil, but ~100us of
// idle-CU time from dispatch shapes):
//  - S + v-proj fused into ONE flat 272-block launch (144 S-role + 128 v-role):
//    v runs in the CUs S leaves idle -> v is free. S output moved to a
//    causal-compact tile layout (36 tiles/batch, 37.75 MB) so it no longer
//    overlays x (which v-role reads) -- race-free by construction.
//  - PV: BN=128 (NFR=2), grid 256 = full chip; end-time set by ti=7 blocks
//    drops ~71 -> ~45 us.
//  - 4 convert kernels fused into 1 (5632 flat blocks); Wv-lo dropped.
//  - phase barrier now followed by explicit s_waitcnt lgkmcnt(0) (m201 exact).
// Core 8-phase pipeline (R5) unchanged: BM=256, BK=64, 8 waves, dbuf LDS,
// counted vmcnt never 0 in steady state, T2 XOR-swizzle, T5 setprio, m204
// bijective XCD swizzle. Numerics identical: q/k/S split-bf16 3-pass
// (K-virtualized), v 1-pass, S fp32, P bf16. Expected absmax 0.015625.
//
// Workspace layout (bytes; total 165,675,008 <= 160 MiB proven bound):
//   xhi  [0,16M) xlo [16M,32M)
//   wqhi [32M,34M) wqlo [34M,36M) wkhi [36M,38M) wklo [38M,40M) wvhi [40M,42M)
//   qhi  [42M,58M) qlo [58M,74M) khi [74M,90M) klo [90M,106M)
//   vthi [106M,122M)                            (vT[b][d][t] bf16)
//   Sc   [122M, 158M)  compact causal S: [b][tri(ti)+tj][256][256] fp32
//   Pbuf overlays qhi/qlo [42M,74M)  (q dead after S)   (M = MiB multiples
//   of exact offsets below)

#define GLOBAL_AS __attribute__((address_space(1)))
#define LDS_AS    __attribute__((address_space(3)))

typedef __attribute__((ext_vector_type(8))) short short8;
typedef __attribute__((ext_vector_type(4))) float f32x4;
typedef long long ll;

__device__ __forceinline__ unsigned short f2bf(float f) {
  unsigned u = __float_as_uint(f);
  u += 0x7FFFu + ((u >> 16) & 1u);   // RTNE (finite values only here)
  return (unsigned short)(u >> 16);
}
__device__ __forceinline__ float bf2f(unsigned short s) {
  return __uint_as_float((unsigned)s << 16);
}
__device__ __forceinline__ void gload_lds16(const unsigned short* g, unsigned short* l) {
  __builtin_amdgcn_global_load_lds((const GLOBAL_AS unsigned int*)g,
                                   (LDS_AS unsigned int*)l, 16, 0, 0);
}

// ---------- fused fp32 -> (bf16 hi[, lo]) split conversion, all 4 inputs ------
__global__ __launch_bounds__(256) void split_all_kernel(
    const float* __restrict__ x, const float* __restrict__ wq,
    const float* __restrict__ wk, const float* __restrict__ wv,
    unsigned short* __restrict__ xhi, unsigned short* __restrict__ xlo,
    unsigned short* __restrict__ wqhi, unsigned short* __restrict__ wqlo,
    unsigned short* __restrict__ wkhi, unsigned short* __restrict__ wklo,
    unsigned short* __restrict__ wvhi) {
  const int id = blockIdx.x;
  const float* src; unsigned short *hi, *lo; int i; bool dolo = true;
  if (id < 4096)      { src = x;  hi = xhi;  lo = xlo;  i = id * 256 + threadIdx.x; }
  else if (id < 4608) { src = wq; hi = wqhi; lo = wqlo; i = (id - 4096) * 256 + threadIdx.x; }
  else if (id < 5120) { src = wk; hi = wkhi; lo = wklo; i = (id - 4608) * 256 + threadIdx.x; }
  else                { src = wv; hi = wvhi; lo = wvhi; i = (id - 5120) * 256 + threadIdx.x; dolo = false; }
  const float4* s4 = (const float4*)src;
  float4 a = s4[2 * i], c = s4[2 * i + 1];
  float v[8] = {a.x, a.y, a.z, a.w, c.x, c.y, c.z, c.w};
  unsigned hw[4], lw[4];
#pragma unroll
  for (int j = 0; j < 4; ++j) {
    unsigned short h0 = f2bf(v[2 * j]),     h1 = f2bf(v[2 * j + 1]);
    unsigned short l0 = f2bf(v[2 * j] - bf2f(h0));
    unsigned short l1 = f2bf(v[2 * j + 1] - bf2f(h1));
    hw[j] = (unsigned)h0 | ((unsigned)h1 << 16);
    lw[j] = (unsigned)l0 | ((unsigned)l1 << 16);
  }
  *(uint4*)(hi + 8 * i) = make_uint4(hw[0], hw[1], hw[2], hw[3]);
  if (dolo) *(uint4*)(lo + 8 * i) = make_uint4(lw[0], lw[1], lw[2], lw[3]);
}

// --------------- 8-phase 256-row A·B^T GEMM (m201 geometry) -------------------
// MODE 0 = qk projection: 256 blocks = 32 ti x 8 tj (tj>>2: 0=q,1=k); 3 passes;
//          split-bf16 out. BN=256.
// MODE 1 = fused S + v-proj: flat 272 blocks. id<144: S-role (b=id/36,
//          triangular (ti,tj)), 3 passes, compact fp32 S out. id>=144: v-role
//          (32 ti x 4 tj), 1 pass, vT bf16 out. BN=256.
// MODE 2 = out = P vT^T: 256 blocks = 4b x 8ti x 8tj; 1 pass; BN=128 (NFR=2);
//          nkb=(ti+1)*4; fp32 out.
template <int MODE>
__global__ __launch_bounds__(512, 2) void gemm8p(
    const unsigned short* __restrict__ A0, const unsigned short* __restrict__ A1,
    const unsigned short* __restrict__ B0, const unsigned short* __restrict__ B1,
    const unsigned short* __restrict__ B2, const unsigned short* __restrict__ B3,
    const unsigned short* __restrict__ Xp, const unsigned short* __restrict__ WVp,
    void* __restrict__ C0, void* __restrict__ C1, void* __restrict__ C2,
    void* __restrict__ C3, void* __restrict__ C4) {
  constexpr int NFR   = (MODE == 2) ? 2 : 4;      // B n-frags per wave
  constexpr int LDA   = (MODE == 2) ? 2048 : 1024;
  constexpr int LDB   = (MODE == 2) ? 2048 : 1024;
  constexpr int BSLOT = (MODE == 2) ? 8192 : 16384;  // shorts per B buffer
  constexpr int BCH   = NFR;                      // B 16B-chunks per thread

  __shared__ __align__(16) unsigned short smA[2 * 16384];
  __shared__ __align__(16) unsigned short smB[2 * BSLOT];

  // m204 bijective XCD swizzle
  const int nwg = gridDim.x, bx0 = blockIdx.x;
  const int q2 = nwg >> 3, r2 = nwg & 7, xcd = bx0 & 7;
  const int id = (xcd < r2 ? xcd * (q2 + 1) : r2 * (q2 + 1) + (xcd - r2) * q2)
                 + (bx0 >> 3);

  int b = 0, ti = 0, tj = 0, nkb = 0, which = 0;
  bool vrole = false;
  const unsigned short *aH, *aL, *bH, *bL;
  if constexpr (MODE == 0) {
    ti = id >> 3; tj = id & 7; which = tj >> 2;
    const int cw = (tj & 3) << 8;
    aH = A0 + (ll)(ti << 8) * 1024; aL = A1 + (ll)(ti << 8) * 1024;
    bH = (which ? B2 : B0) + (ll)cw * 1024;
    bL = (which ? B3 : B1) + (ll)cw * 1024;
    nkb = 48;
  } else if constexpr (MODE == 1) {
    if (id < 144) {            // S-role: triangular (ti,tj), tj<=ti
      b = id / 36; int rem = id - b * 36; int i2 = 0;
      while (rem > i2) { rem -= i2 + 1; ++i2; }
      ti = i2; tj = rem; nkb = 48;
      aH = A0 + (ll)b * 2097152 + (ll)(ti << 8) * 1024;
      aL = A1 + (ll)b * 2097152 + (ll)(ti << 8) * 1024;
      bH = B0 + (ll)b * 2097152 + (ll)(tj << 8) * 1024;
      bL = B1 + (ll)b * 2097152 + (ll)(tj << 8) * 1024;
    } else {                   // v-role: 1 pass, x @ Wv^T -> vT
      vrole = true; const int vid = id - 144;
      ti = vid >> 2; tj = vid & 3; nkb = 16;
      aH = Xp + (ll)(ti << 8) * 1024; aL = aH;
      bH = WVp + (ll)(tj << 8) * 1024; bL = bH;
    }
  } else {                     // MODE 2: PV
    b = id >> 6; const int rest = id & 63;
    ti = rest >> 3; tj = rest & 7; nkb = (ti + 1) << 2;
    aH = A0 + (ll)b * 4194304 + (ll)(ti << 8) * 2048; aL = aH;
    bH = B0 + (ll)b * 2097152 + (ll)(tj << 7) * 2048; bL = bH;
  }

  const int t = threadIdx.x;
  const int lane = t & 63, w = t >> 6;
  const int wm = w >> 2, wn = w & 3;     // 2M x 4N waves, per-wave 128 x 16*NFR
  const int fr = lane & 15, fg = lane >> 4;

  // staging maps (T2: LDS dest linear, GLOBAL source chunk XOR-swizzled)
  int aoff[4], adst[4];
#pragma unroll
  for (int c = 0; c < 4; ++c) {
    const int lin = c * 512 + t, r = lin >> 3, jc = lin & 7;
    adst[c] = lin << 3;
    aoff[c] = r * LDA + ((jc ^ (r & 7)) << 3);
  }
  int boff[BCH], bdst[BCH];
#pragma unroll
  for (int c = 0; c < BCH; ++c) {
    const int lin = c * 512 + t, r = lin >> 3, jc = lin & 7;
    bdst[c] = lin << 3;
    boff[c] = r * LDB + ((jc ^ (r & 7)) << 3);
  }

  auto kmap = [&](int kb, int& p, int& k0) {
    if constexpr (MODE == 2) { p = 0; k0 = kb << 6; }
    else { p = kb >> 4; k0 = (kb & 15) << 6; }   // 3 virtual passes (or 1 if nkb=16)
  };
  auto stageA = [&](int kb) {
    int p, k0; kmap(kb, p, k0);
    const unsigned short* pA = (p == 2) ? aL : aH;
    unsigned short* dst = smA + ((kb & 1) << 14);
#pragma unroll
    for (int c = 0; c < 4; ++c) gload_lds16(pA + aoff[c] + k0, dst + adst[c]);
  };
  auto stageB = [&](int kb, int half) {
    int p, k0; kmap(kb, p, k0);
    const unsigned short* pB = (p == 1) ? bL : bH;
    unsigned short* dst = smB + (kb & 1) * BSLOT;
#pragma unroll
    for (int c = 0; c < BCH / 2; ++c) {
      const int cc = half * (BCH / 2) + c;
      gload_lds16(pB + boff[cc] + k0, dst + bdst[cc]);
    }
  };

  f32x4 acc[8][NFR];
#pragma unroll
  for (int m = 0; m < 8; ++m)
#pragma unroll
    for (int n = 0; n < NFR; ++n) acc[m][n] = (f32x4){0.f, 0.f, 0.f, 0.f};

  // prologue: A0,B0 staged + B1 in flight; wait A0+B0, leave B1 outstanding
  stageA(0); stageB(0, 0); stageB(0, 1); stageB(1, 0); stageB(1, 1);
  if constexpr (MODE == 2) asm volatile("s_waitcnt vmcnt(2)" ::: "memory");
  else                     asm volatile("s_waitcnt vmcnt(4)" ::: "memory");
  __builtin_amdgcn_s_barrier();

  for (int j = 0; j < nkb; ++j) {
    const unsigned short* LA = smA + ((j & 1) << 14);
    const unsigned short* LB = smB + (j & 1) * BSLOT;
    short8 bfrag[NFR][2];
#pragma unroll
    for (int mp = 0; mp < 4; ++mp) {   // 4 phases per K-tile
      short8 af[2][2];
#pragma unroll
      for (int mi = 0; mi < 2; ++mi) {
        const int row = wm * 128 + (mp * 2 + mi) * 16 + fr;
#pragma unroll
        for (int ks = 0; ks < 2; ++ks)
          af[mi][ks] = *(const short8*)(LA + row * 64 + (((ks * 4 + fg) ^ (row & 7)) << 3));
      }
      if (mp == 0) {
#pragma unroll
        for (int n = 0; n < NFR; ++n) {
          const int row = wn * (16 * NFR) + n * 16 + fr;
#pragma unroll
          for (int ks = 0; ks < 2; ++ks)
            bfrag[n][ks] = *(const short8*)(LB + row * 64 + (((ks * 4 + fg) ^ (row & 7)) << 3));
        }
        if (j + 1 < nkb) stageA(j + 1);      // overwrites A(j-1): read-done
      }
      if (mp == 1 && j + 2 < nkb) stageB(j + 2, 0);  // overwrites B(j): read-done @p0
      if (mp == 2 && j + 2 < nkb) stageB(j + 2, 1);
      __builtin_amdgcn_s_barrier();
      asm volatile("s_waitcnt lgkmcnt(0)" ::: "memory");
      __builtin_amdgcn_s_setprio(1);
#pragma unroll
      for (int ks = 0; ks < 2; ++ks)
#pragma unroll
        for (int n = 0; n < NFR; ++n)
#pragma unroll
          for (int mi = 0; mi < 2; ++mi)
            acc[mp * 2 + mi][n] = __builtin_amdgcn_mfma_f32_16x16x32_bf16(
                af[mi][ks], bfrag[n][ks], acc[mp * 2 + mi][n], 0, 0, 0);
      __builtin_amdgcn_s_setprio(0);
      if (mp == 3) {  // one counted wait per K-tile; leaves B(j+2) in flight
        if (j + 2 < nkb) {
          if constexpr (MODE == 2) asm volatile("s_waitcnt vmcnt(2)" ::: "memory");
          else                     asm volatile("s_waitcnt vmcnt(4)" ::: "memory");
        } else if (j + 1 < nkb) {
          asm volatile("s_waitcnt vmcnt(0)" ::: "memory");
        }
      }
      __builtin_amdgcn_s_barrier();
    }
  }

  // ---- epilogue: D layout col=lane&15, row=(lane>>4)*4+jj [m89-verified] ----
#pragma unroll
  for (int m = 0; m < 8; ++m)
#pragma unroll
    for (int n = 0; n < NFR; ++n)
#pragma unroll
      for (int jj = 0; jj < 4; ++jj) {
        const int rloc = wm * 128 + m * 16 + fg * 4 + jj;
        const int colin = wn * (16 * NFR) + n * 16 + fr;
        const float v = acc[m][n][jj];
        if constexpr (MODE == 0) {
          unsigned short* hi = (unsigned short*)(which ? C2 : C0);
          unsigned short* lo = (unsigned short*)(which ? C3 : C1);
          const ll addr = (ll)((ti << 8) + rloc) * 1024 + ((tj & 3) << 8) + colin;
          const unsigned short h = f2bf(v);
          hi[addr] = h;
          lo[addr] = f2bf(v - bf2f(h));
        } else if constexpr (MODE == 1) {
          if (!vrole) {  // compact S: [b][tri(ti)+tj][256][256] fp32
            ((float*)C0)[(ll)b * 2359296 +
                         (ll)(((ti * (ti + 1)) >> 1) + tj) * 65536 +
                         rloc * 256 + colin] = v;
          } else {       // vT[bb][d][tt] bf16
            const int r = (ti << 8) + rloc;
            const int bb = r >> 11, tt = r & 2047;
            ((unsigned short*)C4)[(ll)bb * 2097152 + (ll)((tj << 8) + colin) * 2048 + tt] = f2bf(v);
          }
        } else {
          const int r = (ti << 8) + rloc;
          ((float*)C0)[(ll)b * 2097152 + (ll)r * 1024 + (tj << 7) + colin] = v;
        }
      }
}

// -------- causal row softmax: compact S fp32 -> P bf16 (zero-filled) ----------
__global__ __launch_bounds__(256) void softmax_causal_kernel(
    const float* __restrict__ Sc, unsigned short* __restrict__ P) {
  __shared__ float red[8];
  const int tq = blockIdx.x, b = blockIdx.y, t = threadIdx.x;
  const int ti = tq >> 8;
  const float* srow = Sc + (ll)b * 2359296 + (ll)((ti * (ti + 1)) >> 1) * 65536
                      + (ll)(tq & 255) * 256;   // col i -> srow[(i>>8)*65536 + (i&255)]
  unsigned short* p = P + (ll)b * 4194304 + (ll)tq * 2048;
  const int n = tq + 1;

  float vals[8];
  float mx = -1e30f;
#pragma unroll
  for (int c = 0; c < 8; ++c) {
    const int i = t + c * 256;
    if (i < n) { vals[c] = srow[((i >> 8) << 16) + (i & 255)]; mx = fmaxf(mx, vals[c]); }
  }
#pragma unroll
  for (int o = 32; o > 0; o >>= 1) mx = fmaxf(mx, __shfl_xor(mx, o, 64));
  if ((t & 63) == 0) red[t >> 6] = mx;
  __syncthreads();
  mx = fmaxf(fmaxf(red[0], red[1]), fmaxf(red[2], red[3]));

  float sum = 0.f;
#pragma unroll
  for (int c = 0; c < 8; ++c) {
    const int i = t + c * 256;
    if (i < n) { const float e = __expf(vals[c] - mx); vals[c] = e; sum += e; }
  }
#pragma unroll
  for (int o = 32; o > 0; o >>= 1) sum += __shfl_xor(sum, o, 64);
  if ((t & 63) == 0) red[4 + (t >> 6)] = sum;
  __syncthreads();
  sum = (red[4] + red[5]) + (red[6] + red[7]);
  const float inv = 1.0f / sum;
#pragma unroll
  for (int c = 0; c < 8; ++c) {
    const int i = t + c * 256;
    if (i < n) p[i] = f2bf(vals[c] * inv);
  }
  for (int ii = t; ii < 2048; ii += 256)
    if (ii >= n) p[ii] = 0;  // zero-fill masked cols so PV reads are clean
}

// -------------------------------- launch --------------------------------------
extern "C" void kernel_launch(void* const* d_in, const int* in_sizes, int n_in,
                              void* d_out, int out_size, void* d_ws, size_t ws_size,
                              hipStream_t stream) {
  (void)in_sizes; (void)n_in; (void)out_size; (void)ws_size;
  const float* x  = (const float*)d_in[0];
  const float* Wk = (const float*)d_in[1];  // input order: x, Wk, Wq, Wv
  const float* Wq = (const float*)d_in[2];
  const float* Wv = (const float*)d_in[3];
  char* ws = (char*)d_ws;

  unsigned short* xhi  = (unsigned short*)(ws + 0);
  unsigned short* xlo  = (unsigned short*)(ws + 16777216);
  unsigned short* wqhi = (unsigned short*)(ws + 33554432);
  unsigned short* wqlo = (unsigned short*)(ws + 35651584);
  unsigned short* wkhi = (unsigned short*)(ws + 37748736);
  unsigned short* wklo = (unsigned short*)(ws + 39845888);
  unsigned short* wvhi = (unsigned short*)(ws + 41943040);
  unsigned short* qhi  = (unsigned short*)(ws + 44040192);
  unsigned short* qlo  = (unsigned short*)(ws + 60817408);
  unsigned short* khi  = (unsigned short*)(ws + 77594624);
  unsigned short* klo  = (unsigned short*)(ws + 94371840);
  unsigned short* vthi = (unsigned short*)(ws + 111149056);
  float*          Sc   = (float*)(ws + 127926272);   // 37,748,736 B compact
  unsigned short* Pbuf = (unsigned short*)(ws + 44040192);  // overlays q

  // 1) fused split conversions: x (4096 blk) + Wq,Wk (512 each) + Wv hi (512)
  split_all_kernel<<<5632, 256, 0, stream>>>(
      x, Wq, Wk, Wv, xhi, xlo, wqhi, wqlo, wkhi, wklo, wvhi);

  // 2) q,k projections: 32 row-tiles x 8 col-tiles (4 q | 4 k) = 256 blocks
  gemm8p<0><<<dim3(256, 1), 512, 0, stream>>>(
      xhi, xlo, wqhi, wqlo, wkhi, wklo, nullptr, nullptr,
      qhi, qlo, khi, klo, nullptr);

  // 3) fused S (144 blocks, compact out) + v-proj (128 blocks, vT out)
  gemm8p<1><<<dim3(272, 1), 512, 0, stream>>>(
      qhi, qlo, khi, klo, nullptr, nullptr, xhi, wvhi,
      Sc, nullptr, nullptr, nullptr, vthi);

  // 4) causal softmax: compact S -> P (bf16, zero-filled above diagonal)
  softmax_causal_kernel<<<dim3(2048, 4), 256, 0, stream>>>(Sc, Pbuf);

  // 5) out = P vT^T: 4b x 8ti x 8tj = 256 blocks, BN=128, nkb=(ti+1)*4
  gemm8p<2><<<dim3(256, 1), 512, 0, stream>>>(
      Pbuf, nullptr, vthi, nullptr, nullptr, nullptr, nullptr, nullptr,
      d_out, nullptr, nullptr, nullptr, nullptr);
}

// Round 7
// 380.123 us; speedup vs baseline: 1.2273x; 1.2273x over previous
//
#include <hip/hip_runtime.h>

// Causal attention head: B=4, T=2048, C=1024, fp32 in/out.
//   k = x@Wk^T, q = x@Wq^T, v = x@Wv^T ; S = q@k^T (no scale, causal) ;
//   P = softmax(S) ; out = P@v
//
// R7 (single change vs R6, isolating the regression fix):
//   R6's fused S+v dispatch hit 222us because the m204 XCD swizzle maps
//   CONTIGUOUS id ranges to each XCD -- all 144 long S-role blocks landed on
//   XCDs 0-4 (34 per XCD on 32 CUs -> two sequential 106us S-blocks on some
//   CUs = the 222us), XCDs 5-7 idled on short v-blocks.
//   Fix: MODE 1 uses a role-interleaved XCD-proportional map instead of m204:
//   xcd = bx0&7, l = bx0>>3 (0..33): l<18 -> S-block xcd*18+l (8x18=144),
//   else v-block xcd*16+(l-18) (8x16=128). Every XCD: 18 S + 16 v; S-blocks
//   dispatch first (l ascending), leftover 2 v-blocks backfill ~40us frees.
// Everything else byte-identical to R6: 8-phase 256-row GEMM (BK=64, 8 waves,
// dbuf LDS, counted vmcnt never 0 in steady state, T2 XOR-swizzle, T5
// setprio), m204 swizzle retained for MODE 0/2, compact causal S, fused
// converts, PV BN=128 grid 256. Numerics identical: q/k/S split-bf16 3-pass,
// v 1-pass, S fp32, P bf16. Expected absmax 0.015625.
//
// Workspace layout (bytes; total 165,675,008):
//   xhi  [0,16M) xlo [16M,32M)
//   wqhi [32M,34M) wqlo [34M,36M) wkhi [36M,38M) wklo [38M,40M) wvhi [40M,42M)
//   qhi  [42M,58M) qlo [58M,74M) khi [74M,90M) klo [90M,106M)
//   vthi [106M,122M)                            (vT[b][d][t] bf16)
//   Sc   [122M, 158M)  compact causal S: [b][tri(ti)+tj][256][256] fp32
//   Pbuf overlays qhi/qlo [42M,74M)  (q dead after S)

#define GLOBAL_AS __attribute__((address_space(1)))
#define LDS_AS    __attribute__((address_space(3)))

typedef __attribute__((ext_vector_type(8))) short short8;
typedef __attribute__((ext_vector_type(4))) float f32x4;
typedef long long ll;

__device__ __forceinline__ unsigned short f2bf(float f) {
  unsigned u = __float_as_uint(f);
  u += 0x7FFFu + ((u >> 16) & 1u);   // RTNE (finite values only here)
  return (unsigned short)(u >> 16);
}
__device__ __forceinline__ float bf2f(unsigned short s) {
  return __uint_as_float((unsigned)s << 16);
}
__device__ __forceinline__ void gload_lds16(const unsigned short* g, unsigned short* l) {
  __builtin_amdgcn_global_load_lds((const GLOBAL_AS unsigned int*)g,
                                   (LDS_AS unsigned int*)l, 16, 0, 0);
}

// ---------- fused fp32 -> (bf16 hi[, lo]) split conversion, all 4 inputs ------
__global__ __launch_bounds__(256) void split_all_kernel(
    const float* __restrict__ x, const float* __restrict__ wq,
    const float* __restrict__ wk, const float* __restrict__ wv,
    unsigned short* __restrict__ xhi, unsigned short* __restrict__ xlo,
    unsigned short* __restrict__ wqhi, unsigned short* __restrict__ wqlo,
    unsigned short* __restrict__ wkhi, unsigned short* __restrict__ wklo,
    unsigned short* __restrict__ wvhi) {
  const int id = blockIdx.x;
  const float* src; unsigned short *hi, *lo; int i; bool dolo = true;
  if (id < 4096)      { src = x;  hi = xhi;  lo = xlo;  i = id * 256 + threadIdx.x; }
  else if (id < 4608) { src = wq; hi = wqhi; lo = wqlo; i = (id - 4096) * 256 + threadIdx.x; }
  else if (id < 5120) { src = wk; hi = wkhi; lo = wklo; i = (id - 4608) * 256 + threadIdx.x; }
  else                { src = wv; hi = wvhi; lo = wvhi; i = (id - 5120) * 256 + threadIdx.x; dolo = false; }
  const float4* s4 = (const float4*)src;
  float4 a = s4[2 * i], c = s4[2 * i + 1];
  float v[8] = {a.x, a.y, a.z, a.w, c.x, c.y, c.z, c.w};
  unsigned hw[4], lw[4];
#pragma unroll
  for (int j = 0; j < 4; ++j) {
    unsigned short h0 = f2bf(v[2 * j]),     h1 = f2bf(v[2 * j + 1]);
    unsigned short l0 = f2bf(v[2 * j] - bf2f(h0));
    unsigned short l1 = f2bf(v[2 * j + 1] - bf2f(h1));
    hw[j] = (unsigned)h0 | ((unsigned)h1 << 16);
    lw[j] = (unsigned)l0 | ((unsigned)l1 << 16);
  }
  *(uint4*)(hi + 8 * i) = make_uint4(hw[0], hw[1], hw[2], hw[3]);
  if (dolo) *(uint4*)(lo + 8 * i) = make_uint4(lw[0], lw[1], lw[2], lw[3]);
}

// --------------- 8-phase 256-row A·B^T GEMM (m201 geometry) -------------------
// MODE 0 = qk projection: 256 blocks = 32 ti x 8 tj (tj>>2: 0=q,1=k); 3 passes;
//          split-bf16 out. BN=256. m204 XCD swizzle.
// MODE 1 = fused S + v-proj: flat 272 blocks, role-interleaved XCD map (see
//          header). S-role: triangular (ti,tj), 3 passes, compact fp32 out.
//          v-role: 1 pass, vT bf16 out. BN=256.
// MODE 2 = out = P vT^T: 256 blocks = 4b x 8ti x 8tj; 1 pass; BN=128 (NFR=2);
//          nkb=(ti+1)*4; fp32 out. m204 XCD swizzle.
template <int MODE>
__global__ __launch_bounds__(512, 2) void gemm8p(
    const unsigned short* __restrict__ A0, const unsigned short* __restrict__ A1,
    const unsigned short* __restrict__ B0, const unsigned short* __restrict__ B1,
    const unsigned short* __restrict__ B2, const unsigned short* __restrict__ B3,
    const unsigned short* __restrict__ Xp, const unsigned short* __restrict__ WVp,
    void* __restrict__ C0, void* __restrict__ C1, void* __restrict__ C2,
    void* __restrict__ C3, void* __restrict__ C4) {
  constexpr int NFR   = (MODE == 2) ? 2 : 4;      // B n-frags per wave
  constexpr int LDA   = (MODE == 2) ? 2048 : 1024;
  constexpr int LDB   = (MODE == 2) ? 2048 : 1024;
  constexpr int BSLOT = (MODE == 2) ? 8192 : 16384;  // shorts per B buffer
  constexpr int BCH   = NFR;                      // B 16B-chunks per thread

  __shared__ __align__(16) unsigned short smA[2 * 16384];
  __shared__ __align__(16) unsigned short smB[2 * BSLOT];

  const int bx0 = blockIdx.x;
  int b = 0, ti = 0, tj = 0, nkb = 0, which = 0;
  bool vrole = false;
  const unsigned short *aH, *aL, *bH, *bL;

  if constexpr (MODE == 1) {
    // Role-interleaved XCD-proportional map (R7 fix): blocks round-robin to
    // XCD bx0&7; per-XCD local slot l gets 18 S-roles then 16 v-roles.
    const int xcd = bx0 & 7, l = bx0 >> 3;
    if (l < 18) {              // S-role: triangular (ti,tj), tj<=ti
      const int sid = xcd * 18 + l;          // 0..143
      b = sid / 36; int rem = sid - b * 36; int i2 = 0;
      while (rem > i2) { rem -= i2 + 1; ++i2; }
      ti = i2; tj = rem; nkb = 48;
      aH = A0 + (ll)b * 2097152 + (ll)(ti << 8) * 1024;
      aL = A1 + (ll)b * 2097152 + (ll)(ti << 8) * 1024;
      bH = B0 + (ll)b * 2097152 + (ll)(tj << 8) * 1024;
      bL = B1 + (ll)b * 2097152 + (ll)(tj << 8) * 1024;
    } else {                   // v-role: 1 pass, x @ Wv^T -> vT
      vrole = true; const int vid = xcd * 16 + (l - 18);  // 0..127
      ti = vid >> 2; tj = vid & 3; nkb = 16;
      aH = Xp + (ll)(ti << 8) * 1024; aL = aH;
      bH = WVp + (ll)(tj << 8) * 1024; bL = bH;
    }
  } else {
    // m204 bijective XCD swizzle (homogeneous-duration grids)
    const int nwg = gridDim.x;
    const int q2 = nwg >> 3, r2 = nwg & 7, xcd = bx0 & 7;
    const int id = (xcd < r2 ? xcd * (q2 + 1) : r2 * (q2 + 1) + (xcd - r2) * q2)
                   + (bx0 >> 3);
    if constexpr (MODE == 0) {
      ti = id >> 3; tj = id & 7; which = tj >> 2;
      const int cw = (tj & 3) << 8;
      aH = A0 + (ll)(ti << 8) * 1024; aL = A1 + (ll)(ti << 8) * 1024;
      bH = (which ? B2 : B0) + (ll)cw * 1024;
      bL = (which ? B3 : B1) + (ll)cw * 1024;
      nkb = 48;
    } else {                   // MODE 2: PV
      b = id >> 6; const int rest = id & 63;
      ti = rest >> 3; tj = rest & 7; nkb = (ti + 1) << 2;
      aH = A0 + (ll)b * 4194304 + (ll)(ti << 8) * 2048; aL = aH;
      bH = B0 + (ll)b * 2097152 + (ll)(tj << 7) * 2048; bL = bH;
    }
  }

  const int t = threadIdx.x;
  const int lane = t & 63, w = t >> 6;
  const int wm = w >> 2, wn = w & 3;     // 2M x 4N waves, per-wave 128 x 16*NFR
  const int fr = lane & 15, fg = lane >> 4;

  // staging maps (T2: LDS dest linear, GLOBAL source chunk XOR-swizzled)
  int aoff[4], adst[4];
#pragma unroll
  for (int c = 0; c < 4; ++c) {
    const int lin = c * 512 + t, r = lin >> 3, jc = lin & 7;
    adst[c] = lin << 3;
    aoff[c] = r * LDA + ((jc ^ (r & 7)) << 3);
  }
  int boff[BCH], bdst[BCH];
#pragma unroll
  for (int c = 0; c < BCH; ++c) {
    const int lin = c * 512 + t, r = lin >> 3, jc = lin & 7;
    bdst[c] = lin << 3;
    boff[c] = r * LDB + ((jc ^ (r & 7)) << 3);
  }

  auto kmap = [&](int kb, int& p, int& k0) {
    if constexpr (MODE == 2) { p = 0; k0 = kb << 6; }
    else { p = kb >> 4; k0 = (kb & 15) << 6; }   // 3 virtual passes (or 1 if nkb=16)
  };
  auto stageA = [&](int kb) {
    int p, k0; kmap(kb, p, k0);
    const unsigned short* pA = (p == 2) ? aL : aH;
    unsigned short* dst = smA + ((kb & 1) << 14);
#pragma unroll
    for (int c = 0; c < 4; ++c) gload_lds16(pA + aoff[c] + k0, dst + adst[c]);
  };
  auto stageB = [&](int kb, int half) {
    int p, k0; kmap(kb, p, k0);
    const unsigned short* pB = (p == 1) ? bL : bH;
    unsigned short* dst = smB + (kb & 1) * BSLOT;
#pragma unroll
    for (int c = 0; c < BCH / 2; ++c) {
      const int cc = half * (BCH / 2) + c;
      gload_lds16(pB + boff[cc] + k0, dst + bdst[cc]);
    }
  };

  f32x4 acc[8][NFR];
#pragma unroll
  for (int m = 0; m < 8; ++m)
#pragma unroll
    for (int n = 0; n < NFR; ++n) acc[m][n] = (f32x4){0.f, 0.f, 0.f, 0.f};

  // prologue: A0,B0 staged + B1 in flight; wait A0+B0, leave B1 outstanding
  stageA(0); stageB(0, 0); stageB(0, 1); stageB(1, 0); stageB(1, 1);
  if constexpr (MODE == 2) asm volatile("s_waitcnt vmcnt(2)" ::: "memory");
  else                     asm volatile("s_waitcnt vmcnt(4)" ::: "memory");
  __builtin_amdgcn_s_barrier();

  for (int j = 0; j < nkb; ++j) {
    const unsigned short* LA = smA + ((j & 1) << 14);
    const unsigned short* LB = smB + (j & 1) * BSLOT;
    short8 bfrag[NFR][2];
#pragma unroll
    for (int mp = 0; mp < 4; ++mp) {   // 4 phases per K-tile
      short8 af[2][2];
#pragma unroll
      for (int mi = 0; mi < 2; ++mi) {
        const int row = wm * 128 + (mp * 2 + mi) * 16 + fr;
#pragma unroll
        for (int ks = 0; ks < 2; ++ks)
          af[mi][ks] = *(const short8*)(LA + row * 64 + (((ks * 4 + fg) ^ (row & 7)) << 3));
      }
      if (mp == 0) {
#pragma unroll
        for (int n = 0; n < NFR; ++n) {
          const int row = wn * (16 * NFR) + n * 16 + fr;
#pragma unroll
          for (int ks = 0; ks < 2; ++ks)
            bfrag[n][ks] = *(const short8*)(LB + row * 64 + (((ks * 4 + fg) ^ (row & 7)) << 3));
        }
        if (j + 1 < nkb) stageA(j + 1);      // overwrites A(j-1): read-done
      }
      if (mp == 1 && j + 2 < nkb) stageB(j + 2, 0);  // overwrites B(j): read-done @p0
      if (mp == 2 && j + 2 < nkb) stageB(j + 2, 1);
      __builtin_amdgcn_s_barrier();
      asm volatile("s_waitcnt lgkmcnt(0)" ::: "memory");
      __builtin_amdgcn_s_setprio(1);
#pragma unroll
      for (int ks = 0; ks < 2; ++ks)
#pragma unroll
        for (int n = 0; n < NFR; ++n)
#pragma unroll
          for (int mi = 0; mi < 2; ++mi)
            acc[mp * 2 + mi][n] = __builtin_amdgcn_mfma_f32_16x16x32_bf16(
                af[mi][ks], bfrag[n][ks], acc[mp * 2 + mi][n], 0, 0, 0);
      __builtin_amdgcn_s_setprio(0);
      if (mp == 3) {  // one counted wait per K-tile; leaves B(j+2) in flight
        if (j + 2 < nkb) {
          if constexpr (MODE == 2) asm volatile("s_waitcnt vmcnt(2)" ::: "memory");
          else                     asm volatile("s_waitcnt vmcnt(4)" ::: "memory");
        } else if (j + 1 < nkb) {
          asm volatile("s_waitcnt vmcnt(0)" ::: "memory");
        }
      }
      __builtin_amdgcn_s_barrier();
    }
  }

  // ---- epilogue: D layout col=lane&15, row=(lane>>4)*4+jj [m89-verified] ----
#pragma unroll
  for (int m = 0; m < 8; ++m)
#pragma unroll
    for (int n = 0; n < NFR; ++n)
#pragma unroll
      for (int jj = 0; jj < 4; ++jj) {
        const int rloc = wm * 128 + m * 16 + fg * 4 + jj;
        const int colin = wn * (16 * NFR) + n * 16 + fr;
        const float v = acc[m][n][jj];
        if constexpr (MODE == 0) {
          unsigned short* hi = (unsigned short*)(which ? C2 : C0);
          unsigned short* lo = (unsigned short*)(which ? C3 : C1);
          const ll addr = (ll)((ti << 8) + rloc) * 1024 + ((tj & 3) << 8) + colin;
          const unsigned short h = f2bf(v);
          hi[addr] = h;
          lo[addr] = f2bf(v - bf2f(h));
        } else if constexpr (MODE == 1) {
          if (!vrole) {  // compact S: [b][tri(ti)+tj][256][256] fp32
            ((float*)C0)[(ll)b * 2359296 +
                         (ll)(((ti * (ti + 1)) >> 1) + tj) * 65536 +
                         rloc * 256 + colin] = v;
          } else {       // vT[bb][d][tt] bf16
            const int r = (ti << 8) + rloc;
            const int bb = r >> 11, tt = r & 2047;
            ((unsigned short*)C4)[(ll)bb * 2097152 + (ll)((tj << 8) + colin) * 2048 + tt] = f2bf(v);
          }
        } else {
          const int r = (ti << 8) + rloc;
          ((float*)C0)[(ll)b * 2097152 + (ll)r * 1024 + (tj << 7) + colin] = v;
        }
      }
}

// -------- causal row softmax: compact S fp32 -> P bf16 (zero-filled) ----------
__global__ __launch_bounds__(256) void softmax_causal_kernel(
    const float* __restrict__ Sc, unsigned short* __restrict__ P) {
  __shared__ float red[8];
  const int tq = blockIdx.x, b = blockIdx.y, t = threadIdx.x;
  const int ti = tq >> 8;
  const float* srow = Sc + (ll)b * 2359296 + (ll)((ti * (ti + 1)) >> 1) * 65536
                      + (ll)(tq & 255) * 256;   // col i -> srow[(i>>8)*65536 + (i&255)]
  unsigned short* p = P + (ll)b * 4194304 + (ll)tq * 2048;
  const int n = tq + 1;

  float vals[8];
  float mx = -1e30f;
#pragma unroll
  for (int c = 0; c < 8; ++c) {
    const int i = t + c * 256;
    if (i < n) { vals[c] = srow[((i >> 8) << 16) + (i & 255)]; mx = fmaxf(mx, vals[c]); }
  }
#pragma unroll
  for (int o = 32; o > 0; o >>= 1) mx = fmaxf(mx, __shfl_xor(mx, o, 64));
  if ((t & 63) == 0) red[t >> 6] = mx;
  __syncthreads();
  mx = fmaxf(fmaxf(red[0], red[1]), fmaxf(red[2], red[3]));

  float sum = 0.f;
#pragma unroll
  for (int c = 0; c < 8; ++c) {
    const int i = t + c * 256;
    if (i < n) { const float e = __expf(vals[c] - mx); vals[c] = e; sum += e; }
  }
#pragma unroll
  for (int o = 32; o > 0; o >>= 1) sum += __shfl_xor(sum, o, 64);
  if ((t & 63) == 0) red[4 + (t >> 6)] = sum;
  __syncthreads();
  sum = (red[4] + red[5]) + (red[6] + red[7]);
  const float inv = 1.0f / sum;
#pragma unroll
  for (int c = 0; c < 8; ++c) {
    const int i = t + c * 256;
    if (i < n) p[i] = f2bf(vals[c] * inv);
  }
  for (int ii = t; ii < 2048; ii += 256)
    if (ii >= n) p[ii] = 0;  // zero-fill masked cols so PV reads are clean
}

// -------------------------------- launch --------------------------------------
extern "C" void kernel_launch(void* const* d_in, const int* in_sizes, int n_in,
                              void* d_out, int out_size, void* d_ws, size_t ws_size,
                              hipStream_t stream) {
  (void)in_sizes; (void)n_in; (void)out_size; (void)ws_size;
  const float* x  = (const float*)d_in[0];
  const float* Wk = (const float*)d_in[1];  // input order: x, Wk, Wq, Wv
  const float* Wq = (const float*)d_in[2];
  const float* Wv = (const float*)d_in[3];
  char* ws = (char*)d_ws;

  unsigned short* xhi  = (unsigned short*)(ws + 0);
  unsigned short* xlo  = (unsigned short*)(ws + 16777216);
  unsigned short* wqhi = (unsigned short*)(ws + 33554432);
  unsigned short* wqlo = (unsigned short*)(ws + 35651584);
  unsigned short* wkhi = (unsigned short*)(ws + 37748736);
  unsigned short* wklo = (unsigned short*)(ws + 39845888);
  unsigned short* wvhi = (unsigned short*)(ws + 41943040);
  unsigned short* qhi  = (unsigned short*)(ws + 44040192);
  unsigned short* qlo  = (unsigned short*)(ws + 60817408);
  unsigned short* khi  = (unsigned short*)(ws + 77594624);
  unsigned short* klo  = (unsigned short*)(ws + 94371840);
  unsigned short* vthi = (unsigned short*)(ws + 111149056);
  float*          Sc   = (float*)(ws + 127926272);   // 37,748,736 B compact
  unsigned short* Pbuf = (unsigned short*)(ws + 44040192);  // overlays q

  // 1) fused split conversions: x (4096 blk) + Wq,Wk (512 each) + Wv hi (512)
  split_all_kernel<<<5632, 256, 0, stream>>>(
      x, Wq, Wk, Wv, xhi, xlo, wqhi, wqlo, wkhi, wklo, wvhi);

  // 2) q,k projections: 32 row-tiles x 8 col-tiles (4 q | 4 k) = 256 blocks
  gemm8p<0><<<dim3(256, 1), 512, 0, stream>>>(
      xhi, xlo, wqhi, wqlo, wkhi, wklo, nullptr, nullptr,
      qhi, qlo, khi, klo, nullptr);

  // 3) fused S (144 blocks, compact out) + v-proj (128 blocks, vT out),
  //    role-interleaved XCD map (18 S + 16 v per XCD)
  gemm8p<1><<<dim3(272, 1), 512, 0, stream>>>(
      qhi, qlo, khi, klo, nullptr, nullptr, xhi, wvhi,
      Sc, nullptr, nullptr, nullptr, vthi);

  // 4) causal softmax: compact S -> P (bf16, zero-filled above diagonal)
  softmax_causal_kernel<<<dim3(2048, 4), 256, 0, stream>>>(Sc, Pbuf);

  // 5) out = P vT^T: 4b x 8ti x 8tj = 256 blocks, BN=128, nkb=(ti+1)*4
  gemm8p<2><<<dim3(256, 1), 512, 0, stream>>>(
      Pbuf, nullptr, vthi, nullptr, nullptr, nullptr, nullptr, nullptr,
      d_out, nullptr, nullptr, nullptr, nullptr);
}